// Round 9
// baseline (123.375 us; speedup 1.0000x reference)
//
#include <hip/hip_runtime.h>

// Chamfer distance, B=16, N=M=4096, D=3.
// dist(i,j) = n1 + n2 - 2*x1.x2 as ONE bf16 MFMA per 32x32 tile (norms folded
// into padded K slots, hi/lo bf16 split => exact-grade; absmax 0.0 since R1).
// R9: R8's 5000 cyc/phase traced to lds[p&1] dynamic indexing -> alias
// analysis fails -> compiler emits vmcnt(0) before every phase's ds_reads,
// serializing prefetch. Fix: TWO named __shared__ buffers + fully-unrolled
// 4-phase straight-line schedule (buffer identity compile-time), and 32-tile
// phases so compute (~1200 cyc) >= load latency even in the worst case.
// 64 KB LDS -> 2 blocks/CU, (256,2) -> 256-reg budget (no spill pressure).

typedef __attribute__((ext_vector_type(8))) __bf16 bf16x8;
typedef __attribute__((ext_vector_type(16))) float f32x16;

#define PTS 4096
#define TILES 128   // PTS/32
#define NB 16

__device__ __forceinline__ unsigned f2bf(float f) {
  unsigned u = __float_as_uint(f);
  return (u + 0x7FFFu + ((u >> 16) & 1u)) >> 16;  // RNE bf16 bits
}
__device__ __forceinline__ float bf2f(unsigned s) {
  return __uint_as_float(s << 16);
}
__device__ __forceinline__ unsigned pk(unsigned lo, unsigned hi) {
  return (lo & 0xFFFFu) | (hi << 16);
}
__device__ __forceinline__ void gload_lds16(const void* g, void* l) {
  __builtin_amdgcn_global_load_lds(
      (const __attribute__((address_space(1))) unsigned*)g,
      (__attribute__((address_space(3))) unsigned*)l, 16, 0, 0);
}

// ---- prepack B-side fragments + zero out[] ----
// Bfr slab (d,b): 128 tiles x 1 KB, tile t = [half0: 32x16B][half1: 32x16B].
// B k-vec: w0=[Hx Hy Hz Lx Ly Lz Hx Hy]  w1=[Hz nh nl 1 1 0 0 0], H,L split -2q.
__global__ __launch_bounds__(256) void prepack_b(const float* __restrict__ x1,
                                                 const float* __restrict__ x2,
                                                 uint4* __restrict__ Bfr,
                                                 float* __restrict__ out) {
  const int id = blockIdx.x * 256 + threadIdx.x;  // 2*NB*PTS = 131072
  if (id < NB) out[id] = 0.f;                     // main accumulates into out
  const int d = id >> 16;
  const int b = (id >> 12) & (NB - 1);
  const int j = id & (PTS - 1);
  const float* q = (d ? x1 : x2) + (size_t)(b * PTS + j) * 3;
  const float x = q[0], y = q[1], z = q[2];
  const float sx = -2.f * x, sy = -2.f * y, sz = -2.f * z;
  const unsigned Hx = f2bf(sx), Hy = f2bf(sy), Hz = f2bf(sz);
  const unsigned Lx = f2bf(sx - bf2f(Hx));
  const unsigned Ly = f2bf(sy - bf2f(Hy));
  const unsigned Lz = f2bf(sz - bf2f(Hz));
  const float n = fmaf(x, x, fmaf(y, y, z * z));
  const unsigned nh = f2bf(n), nl = f2bf(n - bf2f(nh));
  const unsigned one = 0x3F80u;
  uint4 w0, w1;
  w0.x = pk(Hx, Hy); w0.y = pk(Hz, Lx); w0.z = pk(Ly, Lz); w0.w = pk(Hx, Hy);
  w1.x = pk(Hz, nh); w1.y = pk(nl, one); w1.z = pk(one, 0u); w1.w = 0u;
  uint4* base = Bfr + ((size_t)((d * NB + b) * TILES + (j >> 5))) * 64 + (j & 31);
  base[0]  = w0;   // half 0
  base[32] = w1;   // half 1
}

// ---- main: 4 waves/block; wave = 1 row-tile (32 rows) x all 128 col-tiles.
// Four 32-tile phases, ping-pong across two NAMED 32 KB LDS buffers.
__global__ __launch_bounds__(256, 2) void chamfer_main(
    const float* __restrict__ x1, const float* __restrict__ x2,
    const uint4* __restrict__ Bfr, float* __restrict__ out) {
  __shared__ __align__(16) uint4 B0[32 * 64];  // 32 KB (32 tiles)
  __shared__ __align__(16) uint4 B1[32 * 64];  // 32 KB

  const int rg = blockIdx.x;           // 32 row-groups of 128 rows
  const int d  = blockIdx.y >> 4;      // direction
  const int b  = blockIdx.y & (NB - 1);

  const int tid  = threadIdx.x;
  const int lane = tid & 63;
  const int half = lane >> 5;          // K-half this lane supplies to MFMA
  const int l31  = lane & 31;
  const int wave = tid >> 6;

  // --- build A fragment from raw points (row tile t0, row = t0*32 + l31) ---
  // A k-vec: w0=[hx hy hz hx hy hz lx ly]  w1=[lz 1 1 nh nl 0 0 0]
  const float* P = d ? x2 : x1;
  const int t0 = rg * 4 + wave;
  bf16x8 af;
  {
    const int r = t0 * 32 + l31;
    const float* p = P + (size_t)(b * PTS + r) * 3;
    const float x = p[0], y = p[1], zc = p[2];
    const unsigned hx = f2bf(x), hy = f2bf(y), hz = f2bf(zc);
    const unsigned lx = f2bf(x - bf2f(hx));
    const unsigned ly = f2bf(y - bf2f(hy));
    const unsigned lz = f2bf(zc - bf2f(hz));
    const float n = fmaf(x, x, fmaf(y, y, zc * zc));
    const unsigned nh = f2bf(n), nl = f2bf(n - bf2f(nh));
    const unsigned one = 0x3F80u;
    uint4 w0, w1;
    w0.x = pk(hx, hy); w0.y = pk(hz, hx); w0.z = pk(hy, hz); w0.w = pk(lx, ly);
    w1.x = pk(lz, one); w1.y = pk(one, nh); w1.z = pk(nl, 0u); w1.w = 0u;
    uint4 w;
    w.x = half ? w1.x : w0.x; w.y = half ? w1.y : w0.y;
    w.z = half ? w1.z : w0.z; w.w = half ? w1.w : w0.w;
    af = *(const bf16x8*)&w;
  }

  f32x16 zero;
#pragma unroll
  for (int e = 0; e < 16; ++e) zero[e] = 0.f;

  float rm[16];
#pragma unroll
  for (int e = 0; e < 16; ++e) rm[e] = 3.0e38f;

  const char* slab = (const char*)(Bfr + (size_t)((d * NB + b) * TILES) * 64);
  const size_t lgoff = (size_t)lane * 16;   // lane's 16B within a tile
  const int foff = half * 32 + l31;         // lane's uint4 index within a tile

  // stage(phase) into buf: each wave stages its 8 of the phase's 32 tiles
  auto stage = [&](uint4* buf, int phase) {
    const char* g = slab + ((size_t)phase * 32 + wave * 8) * 1024 + lgoff;
    char* l = (char*)(buf + (size_t)(wave * 8) * 64);
#pragma unroll
    for (int k = 0; k < 8; ++k)
      gload_lds16(g + k * 1024, l + k * 1024);
  };
  // compute: 32 tiles, ds_read_b128 pairs -> 2 MFMA -> 16 v_min3 folds
  auto compute = [&](const uint4* buf) {
    const uint4* bp = buf + foff;
#pragma unroll
    for (int t = 0; t < 32; t += 2) {
      const bf16x8 f0 = *(const bf16x8*)(bp + t * 64);
      const bf16x8 f1 = *(const bf16x8*)(bp + (t + 1) * 64);
      const f32x16 a0 =
          __builtin_amdgcn_mfma_f32_32x32x16_bf16(af, f0, zero, 0, 0, 0);
      const f32x16 a1 =
          __builtin_amdgcn_mfma_f32_32x32x16_bf16(af, f1, zero, 0, 0, 0);
#pragma unroll
      for (int e = 0; e < 16; ++e)
        rm[e] = fminf(fminf(a0[e], a1[e]), rm[e]);  // v_min3_f32
    }
  };

  // 4 phases, straight-line, compile-time buffer identity:
  stage(B0, 0);
  __syncthreads();            // B0 resident
  stage(B1, 1);               // prefetch in flight during compute(B0)
  compute(B0);
  __syncthreads();            // B1 resident; all waves done reading B0
  stage(B0, 2);
  compute(B1);
  __syncthreads();            // B0 resident; all waves done reading B1
  stage(B1, 3);
  compute(B0);
  __syncthreads();            // B1 resident
  compute(B1);

  // --- epilogue: full row mins (butterfly over 32 cols), sum, one atomicAdd.
  // C/D layout: col = lane&31, row_local = (e&3) + 8*(e>>2) + 4*half.
  float ssum = 0.f;
#pragma unroll
  for (int e = 0; e < 16; ++e) {
    float v = rm[e];
    v = fminf(v, __shfl_xor(v, 1));
    v = fminf(v, __shfl_xor(v, 2));
    v = fminf(v, __shfl_xor(v, 4));
    v = fminf(v, __shfl_xor(v, 8));
    v = fminf(v, __shfl_xor(v, 16));
    ssum += v;  // each e is a distinct row of this lane-half
  }
  ssum += __shfl_xor(ssum, 32);  // combine the two 16-row lane halves
  if (lane == 0) atomicAdd(&out[b], ssum * (1.0f / (float)PTS));
}

extern "C" void kernel_launch(void* const* d_in, const int* in_sizes, int n_in,
                              void* d_out, int out_size, void* d_ws,
                              size_t ws_size, hipStream_t stream) {
  const float* x1 = (const float*)d_in[0];
  const float* x2 = (const float*)d_in[1];
  float* out = (float*)d_out;

  uint4* Bfr = (uint4*)d_ws;  // 2*NB*TILES*64 uint4 = 4 MB

  prepack_b<<<(2 * NB * PTS) / 256, 256, 0, stream>>>(x1, x2, Bfr, out);
  dim3 grid(PTS / 128, 2 * NB);  // x = row-group ; y = dir*16 + batch
  chamfer_main<<<grid, 256, 0, stream>>>(x1, x2, Bfr, out);
}